// Round 14
// baseline (163.190 us; speedup 1.0000x reference)
//
#include <hip/hip_runtime.h>
#include <hip/hip_bf16.h>

#define S_ 4
#define H_ 1024
#define D_ 256
#define B_ 8
#define N_ 1024
#define R_ (B_*N_)   /* 8192 */
#define EPS_ 1e-8f

typedef float f32x4 __attribute__((ext_vector_type(4)));
typedef short bf16x8 __attribute__((ext_vector_type(8)));
typedef unsigned short u16;

__device__ __forceinline__ u16 f2b(float f) {
    union { __bf16 h; u16 u; } cv; cv.h = (__bf16)f; return cv.u;
}

__device__ __forceinline__ void gload16(const void* g, void* l) {
    __builtin_amdgcn_global_load_lds((const __attribute__((address_space(1))) void*)g,
                                     (__attribute__((address_space(3))) void*)l, 16, 0, 0);
}

// T1 XCD-chunked remaps (bijective; assumes bid%8 XCD round-robin dispatch).
__device__ __forceinline__ int xcd_wgid512(int bid) {
    return (bid & 7) * 64 + (bid >> 3);
}
__device__ __forceinline__ int xcd_wgid256(int bid) {
    return (bid & 7) * 32 + (bid >> 3);
}

// ---------------- prep (merged): Wp^T, Wr^T, brsum in one launch ----------------
__device__ __forceinline__ void tc64(const float* __restrict__ src, int lds_,
                                     u16* __restrict__ dst, int ldd) {
    __shared__ float t[64][65];
    const int tid = threadIdx.x;
    const int rr = tid >> 4;
    const int cc = (tid & 15) * 4;
    #pragma unroll
    for (int p = 0; p < 4; ++p) {
        const int r = rr + p * 16;
        const float4 v = *(const float4*)(src + (size_t)r * lds_ + cc);
        t[r][cc] = v.x; t[r][cc + 1] = v.y; t[r][cc + 2] = v.z; t[r][cc + 3] = v.w;
    }
    __syncthreads();
    #pragma unroll
    for (int p = 0; p < 4; ++p) {
        const int c = rr + p * 16;
        union { u16 u[4]; uint2 v; } o;
        o.u[0] = f2b(t[cc + 0][c]); o.u[1] = f2b(t[cc + 1][c]);
        o.u[2] = f2b(t[cc + 2][c]); o.u[3] = f2b(t[cc + 3][c]);
        *(uint2*)(dst + (size_t)c * ldd + cc) = o.v;
    }
}

__global__ __launch_bounds__(256) void k_prep(
    const float* __restrict__ Wp, const float* __restrict__ Wr, const float* __restrict__ br,
    u16* __restrict__ WpT, u16* __restrict__ WrT, float* __restrict__ brsum)
{
    const int bid = blockIdx.x;
    if (bid < 256) {                       // Wp transpose
        const int s = bid >> 6;
        const int r0 = (bid & 15) * 64;    // h
        const int c0 = ((bid >> 4) & 3) * 64;  // d
        tc64(Wp + (size_t)s * H_ * D_ + (size_t)r0 * D_ + c0, D_,
             WpT + (size_t)s * D_ * H_ + (size_t)c0 * H_ + r0, H_);
    } else if (bid < 512) {                // Wr transpose
        const int b2 = bid - 256;
        const int c0 = (b2 & 15) * 64;     // h
        const int r0 = (b2 >> 4) * 64;     // sd
        tc64(Wr + (size_t)r0 * H_ + c0, H_,
             WrT + (size_t)c0 * H_ + r0, H_);
    } else {                               // brsum
        const int h = (bid - 512) * 256 + threadIdx.x;
        if (h < H_) brsum[h] = br[h] + br[H_ + h] + br[2 * H_ + h] + br[3 * H_ + h];
    }
}

// ---------------- bf16 64x64 transpose: araw [r][s*256+d] -> arawT [(s,b)][d][j] ----------------
__global__ __launch_bounds__(256) void k_tc_araw(const u16* __restrict__ src, u16* __restrict__ dst) {
    const int sb = blockIdx.z, s = sb >> 3, b = sb & 7;
    const int j0 = blockIdx.x * 64, d0 = blockIdx.y * 64;
    __shared__ u16 tile[64][68];
    const int t = threadIdx.x;
    const int r = t >> 4, c4 = (t & 15) * 4;
    #pragma unroll
    for (int p = 0; p < 4; ++p) {
        const int row = p * 16 + r;
        *(uint2*)&tile[row][c4] =
            *(const uint2*)(src + (size_t)(b * N_ + j0 + row) * 1024 + s * 256 + d0 + c4);
    }
    __syncthreads();
    #pragma unroll
    for (int p = 0; p < 4; ++p) {
        const int orow = p * 16 + r;      // d-index
        union { u16 u[4]; uint2 v; } o;
        o.u[0] = tile[c4 + 0][orow]; o.u[1] = tile[c4 + 1][orow];
        o.u[2] = tile[c4 + 2][orow]; o.u[3] = tile[c4 + 3][orow];
        *(uint2*)(dst + ((size_t)sb << 18) + (size_t)(d0 + orow) * 1024 + j0 + c4) = o.v;
    }
}

// ============ reusable dbuf BK=64 GEMM core: C = A(TMxK) . B^T(TNxK) ============
template<int WROWS, int WCOLS, int MFR, int NFR>
__device__ __forceinline__ void gemm_dbuf(
    const u16* __restrict__ Ag, const u16* __restrict__ Bg,
    int lda, int ldb, int K, u16* SA, u16* SB, f32x4 (&acc)[MFR][NFR])
{
    constexpr int NT = WROWS * WCOLS * 64;
    constexpr int TM = WROWS * MFR * 16;
    constexpr int TN = WCOLS * NFR * 16;
    constexpr int CA = TM * 8 / NT;       // 16B chunks per thread for A
    constexpr int CB = TN * 8 / NT;
    constexpr int L  = CA + CB;           // vmem instrs per STAGE per thread
    const int tid = threadIdx.x, l = tid & 63, wv = tid >> 6;
    const int wm = wv / WCOLS, wn = wv % WCOLS;
    const int nsteps = K / 64;

    auto STAGE = [&](int buf, int k0) {
        #pragma unroll
        for (int i = 0; i < CA; ++i) {
            const int ci = i * NT + tid;
            const int row = ci >> 3, c = ci & 7, cs = c ^ (row & 7);
            gload16(Ag + (size_t)row * lda + k0 + cs * 8, SA + buf * TM * 64 + ci * 8);
        }
        #pragma unroll
        for (int i = 0; i < CB; ++i) {
            const int ci = i * NT + tid;
            const int row = ci >> 3, c = ci & 7, cs = c ^ (row & 7);
            gload16(Bg + (size_t)row * ldb + k0 + cs * 8, SB + buf * TN * 64 + ci * 8);
        }
    };

    STAGE(0, 0);
    for (int t = 0; t < nsteps; ++t) {
        const int cur = t & 1;
        if (t < nsteps - 1) {
            STAGE(cur ^ 1, (t + 1) * 64);
            if constexpr (L == 3)      asm volatile("s_waitcnt vmcnt(3)" ::: "memory");
            else if constexpr (L == 6) asm volatile("s_waitcnt vmcnt(6)" ::: "memory");
            else if constexpr (L == 8) asm volatile("s_waitcnt vmcnt(8)" ::: "memory");
            else                       asm volatile("s_waitcnt vmcnt(0)" ::: "memory");
        } else {
            asm volatile("s_waitcnt vmcnt(0)" ::: "memory");
        }
        __builtin_amdgcn_s_barrier();
        __builtin_amdgcn_sched_barrier(0);
        bf16x8 af[2][MFR], bq[2][NFR];
        #pragma unroll
        for (int kc = 0; kc < 2; ++kc) {
            #pragma unroll
            for (int m = 0; m < MFR; ++m) {
                const int r = wm * MFR * 16 + m * 16 + (l & 15);
                const int c = (kc * 4 + (l >> 4)) ^ (r & 7);
                af[kc][m] = *(const bf16x8*)(SA + cur * TM * 64 + r * 64 + c * 8);
            }
            #pragma unroll
            for (int n = 0; n < NFR; ++n) {
                const int r = wn * NFR * 16 + n * 16 + (l & 15);
                const int c = (kc * 4 + (l >> 4)) ^ (r & 7);
                bq[kc][n] = *(const bf16x8*)(SB + cur * TN * 64 + r * 64 + c * 8);
            }
        }
        asm volatile("s_waitcnt lgkmcnt(0)" ::: "memory");
        __builtin_amdgcn_s_barrier();
        __builtin_amdgcn_sched_barrier(0);
        #pragma unroll
        for (int kc = 0; kc < 2; ++kc)
            #pragma unroll
            for (int m = 0; m < MFR; ++m)
                #pragma unroll
                for (int n = 0; n < NFR; ++n)
                    acc[m][n] = __builtin_amdgcn_mfma_f32_16x16x32_bf16(af[kc][m], bq[kc][n], acc[m][n], 0, 0, 0);
    }
}

// ---------------- proj (fused norm) v7 + T1 remap: fp32-direct A, BK=32 dbuf ----------------
__global__ __launch_bounds__(512, 4) void k_proj_norm(
    const float* __restrict__ hx, const float* __restrict__ ha,
    const u16* __restrict__ WpT, const float* __restrict__ bp,
    u16* __restrict__ xnb, u16* __restrict__ araw, float* __restrict__ inv_na)
{
    __shared__ u16 SA[2][128][32];     // 16 KB
    __shared__ u16 SB[2][256][32];     // 32 KB
    __shared__ float normbuf[128][4];  //  2 KB

    const int wgid = xcd_wgid512(blockIdx.x);
    const int s    = wgid & 3;
    const int is_a = (wgid >> 2) & 1;
    const int rt   = (wgid >> 3) * 128;
    const int tid = threadIdx.x;
    const int l = tid & 63, wv = tid >> 6;
    const int wm = wv >> 2, wn = wv & 3;  // 2 x 4, wave tile 64x64
    const float* __restrict__ Ag = (is_a ? ha : hx) + (size_t)rt * 1024;
    const u16* __restrict__ Bg = WpT + (size_t)(s * 256) * 1024;

    const int arow = tid >> 2, aslot = tid & 3;
    const int acs  = (aslot - (arow >> 1)) & 3;
    const float* __restrict__ Ap = Ag + (size_t)arow * 1024 + acs * 8;

    f32x4 acc[4][4];
    #pragma unroll
    for (int m = 0; m < 4; ++m)
        #pragma unroll
        for (int n = 0; n < 4; ++n) acc[m][n] = (f32x4){0.f, 0.f, 0.f, 0.f};

    float4 a0[2], a1[2];   // two A reg sets (tile parity)
    auto ALOAD = [&](float4 (&r)[2], int k0) {
        r[0] = *(const float4*)(Ap + k0);
        r[1] = *(const float4*)(Ap + k0 + 4);
    };
    auto AWRITE = [&](const float4 (&r)[2], int buf) {
        union { u16 u[8]; uint4 v; } o;
        o.u[0] = f2b(r[0].x); o.u[1] = f2b(r[0].y); o.u[2] = f2b(r[0].z); o.u[3] = f2b(r[0].w);
        o.u[4] = f2b(r[1].x); o.u[5] = f2b(r[1].y); o.u[6] = f2b(r[1].z); o.u[7] = f2b(r[1].w);
        *(uint4*)&SA[buf][arow][aslot * 8] = o.v;
    };
    auto BSTAGE = [&](int buf, int k0) {
        #pragma unroll
        for (int i = 0; i < 2; ++i) {
            const int ci = i * 512 + tid;
            const int row = ci >> 2, c = ci & 3, cs = (c - (row >> 1)) & 3;
            gload16(Bg + (size_t)row * 1024 + k0 + cs * 8, &SB[buf][row][c * 8]);
        }
    };
    auto COMPUTE = [&](int cur) {
        bf16x8 af[4], bq[4];
        #pragma unroll
        for (int m = 0; m < 4; ++m) {
            const int r = wm * 64 + m * 16 + (l & 15);
            const int c = ((l >> 4) + (r >> 1)) & 3;
            af[m] = *(const bf16x8*)&SA[cur][r][c * 8];
        }
        #pragma unroll
        for (int n = 0; n < 4; ++n) {
            const int r = wn * 64 + n * 16 + (l & 15);
            const int c = ((l >> 4) + (r >> 1)) & 3;
            bq[n] = *(const bf16x8*)&SB[cur][r][c * 8];
        }
        asm volatile("s_waitcnt lgkmcnt(0)" ::: "memory");
        __builtin_amdgcn_sched_barrier(0);
        __builtin_amdgcn_s_barrier();        // free cur for next iter's staging
        __builtin_amdgcn_sched_barrier(0);
        #pragma unroll
        for (int m = 0; m < 4; ++m)
            #pragma unroll
            for (int n = 0; n < 4; ++n)
                acc[m][n] = __builtin_amdgcn_mfma_f32_16x16x32_bf16(af[m], bq[n], acc[m][n], 0, 0, 0);
    };
    auto BODY = [&](int t, float4 (&wset)[2], float4 (&lset)[2], int cur, bool doload) {
        asm volatile("s_waitcnt vmcnt(2)" ::: "memory");   // retire A(t+1) (oldest 2)
        __builtin_amdgcn_sched_barrier(0);
        AWRITE(wset, cur ^ 1);
        if (doload) ALOAD(lset, (t + 2) * 32);
        BSTAGE(cur ^ 1, (t + 1) * 32);
        if (doload) asm volatile("s_waitcnt vmcnt(4)" ::: "memory");  // retire B(t)
        else        asm volatile("s_waitcnt vmcnt(2)" ::: "memory");
        asm volatile("s_waitcnt lgkmcnt(0)" ::: "memory"); // A(t) writes visible
        __builtin_amdgcn_sched_barrier(0);
        __builtin_amdgcn_s_barrier();        // publish tile t
        __builtin_amdgcn_sched_barrier(0);
        COMPUTE(cur);
    };

    ALOAD(a0, 0);
    ALOAD(a1, 32);
    BSTAGE(0, 0);
    asm volatile("s_waitcnt vmcnt(4)" ::: "memory");       // retire A(0)
    __builtin_amdgcn_sched_barrier(0);
    AWRITE(a0, 0);

    for (int tt = 0; tt < 30; tt += 2) {
        BODY(tt,     a1, a0, 0, true);
        BODY(tt + 1, a0, a1, 1, true);
    }
    BODY(30, a1, a0, 0, false);
    asm volatile("s_waitcnt vmcnt(0)" ::: "memory");
    asm volatile("s_waitcnt lgkmcnt(0)" ::: "memory");
    __builtin_amdgcn_sched_barrier(0);
    __builtin_amdgcn_s_barrier();
    __builtin_amdgcn_sched_barrier(0);
    COMPUTE(1);

    // ---- epilogue: bias, row L2-norm over the 256-col subspace, write bf16 ----
    float bv[4];
    #pragma unroll
    for (int n = 0; n < 4; ++n) bv[n] = bp[s * 256 + wn * 64 + n * 16 + (l & 15)];
    #pragma unroll
    for (int m = 0; m < 4; ++m)
        #pragma unroll
        for (int n = 0; n < 4; ++n)
            #pragma unroll
            for (int q = 0; q < 4; ++q) acc[m][n][q] += bv[n];

    float ss[4][4];
    #pragma unroll
    for (int m = 0; m < 4; ++m)
        #pragma unroll
        for (int q = 0; q < 4; ++q) {
            float v = 0.f;
            #pragma unroll
            for (int n = 0; n < 4; ++n) v += acc[m][n][q] * acc[m][n][q];
            ss[m][q] = v;
        }
    #pragma unroll
    for (int off = 1; off <= 8; off <<= 1)
        #pragma unroll
        for (int m = 0; m < 4; ++m)
            #pragma unroll
            for (int q = 0; q < 4; ++q) ss[m][q] += __shfl_xor(ss[m][q], off, 64);
    if ((l & 15) == 0) {
        #pragma unroll
        for (int m = 0; m < 4; ++m)
            #pragma unroll
            for (int q = 0; q < 4; ++q)
                normbuf[wm * 64 + m * 16 + (l >> 4) * 4 + q][wn] = ss[m][q];
    }
    __syncthreads();
    float sc[4][4];
    #pragma unroll
    for (int m = 0; m < 4; ++m)
        #pragma unroll
        for (int q = 0; q < 4; ++q) {
            const int rl = wm * 64 + m * 16 + (l >> 4) * 4 + q;
            const float tot = normbuf[rl][0] + normbuf[rl][1] + normbuf[rl][2] + normbuf[rl][3];
            sc[m][q] = 1.0f / fmaxf(sqrtf(tot), EPS_);
        }
    if (!is_a) {
        #pragma unroll
        for (int m = 0; m < 4; ++m)
            #pragma unroll
            for (int n = 0; n < 4; ++n)
                #pragma unroll
                for (int q = 0; q < 4; ++q) {
                    const int rl = wm * 64 + m * 16 + (l >> 4) * 4 + q;
                    xnb[(size_t)(rt + rl) * 1024 + s * 256 + wn * 64 + n * 16 + (l & 15)] =
                        f2b(acc[m][n][q] * sc[m][q]);
                }
    } else {
        #pragma unroll
        for (int m = 0; m < 4; ++m)
            #pragma unroll
            for (int n = 0; n < 4; ++n)
                #pragma unroll
                for (int q = 0; q < 4; ++q) {
                    const int rl = wm * 64 + m * 16 + (l >> 4) * 4 + q;
                    araw[(size_t)(rt + rl) * 1024 + s * 256 + wn * 64 + n * 16 + (l & 15)] =
                        f2b(acc[m][n][q]);
                }
        if (wn == 0 && (l & 15) == 0) {
            #pragma unroll
            for (int m = 0; m < 4; ++m)
                #pragma unroll
                for (int q = 0; q < 4; ++q) {
                    const int rl = wm * 64 + m * 16 + (l >> 4) * 4 + q;
                    inv_na[s * R_ + rt + rl] = sc[m][q];
                }
        }
    }
}

// ---------------- sim v3 + T1 remap: TM=64, dbuf, fused softmax(s) ----------------
__global__ __launch_bounds__(512, 4) void k_sim_v3(
    const u16* __restrict__ xnb, const u16* __restrict__ araw,
    const float* __restrict__ inv_na, u16* __restrict__ whalf, const int half)
{
    __shared__ u16 SmA[2 * 64 * 64];
    __shared__ u16 SmB[2 * 128 * 64];
    const int wgid = xcd_wgid512(blockIdx.x);
    const int jt   = (wgid & 7) * 128;
    const int itl  = ((wgid >> 3) & 7) * 64;
    const int b    = wgid >> 6;
    const int it  = half * 512 + itl;
    const int tid = threadIdx.x, l = tid & 63, wv = tid >> 6;  // 8 waves
    const int wi = wv >> 2, wj = wv & 3;         // 2 x 4 -> wave tile 32 x 32 (per s)
    const u16* __restrict__ Ag = xnb  + (size_t)(b * N_ + it) * 1024;
    const u16* __restrict__ Bg = araw + (size_t)(b * N_ + jt) * 1024;

    f32x4 acc[4][2][2];  // [s][m][n]
    #pragma unroll
    for (int s = 0; s < 4; ++s)
        #pragma unroll
        for (int m = 0; m < 2; ++m)
            #pragma unroll
            for (int n = 0; n < 2; ++n) acc[s][m][n] = (f32x4){0.f, 0.f, 0.f, 0.f};

    auto STAGE = [&](int buf, int t) {
        const int k0 = t * 64;
        {
            const int ci = tid;
            const int row = ci >> 3, c = ci & 7, cs = c ^ (row & 7);
            gload16(Ag + (size_t)row * 1024 + k0 + cs * 8, SmA + buf * 4096 + ci * 8);
        }
        #pragma unroll
        for (int i = 0; i < 2; ++i) {
            const int ci = i * 512 + tid;
            const int row = ci >> 3, c = ci & 7, cs = c ^ (row & 7);
            gload16(Bg + (size_t)row * 1024 + k0 + cs * 8, SmB + buf * 8192 + ci * 8);
        }
    };

    STAGE(0, 0);
    #pragma unroll
    for (int s = 0; s < 4; ++s) {
        #pragma unroll
        for (int kk = 0; kk < 4; ++kk) {
            const int t = s * 4 + kk;
            const int cur = t & 1;
            if (t < 15) {
                STAGE(cur ^ 1, t + 1);
                asm volatile("s_waitcnt vmcnt(3)" ::: "memory");
            } else {
                asm volatile("s_waitcnt vmcnt(0)" ::: "memory");
            }
            __builtin_amdgcn_s_barrier();
            __builtin_amdgcn_sched_barrier(0);
            bf16x8 af[2][2], bq[2][2];
            #pragma unroll
            for (int kc = 0; kc < 2; ++kc) {
                #pragma unroll
                for (int m = 0; m < 2; ++m) {
                    const int r = wi * 32 + m * 16 + (l & 15);
                    const int c = (kc * 4 + (l >> 4)) ^ (r & 7);
                    af[kc][m] = *(const bf16x8*)(SmA + cur * 4096 + r * 64 + c * 8);
                }
                #pragma unroll
                for (int n = 0; n < 2; ++n) {
                    const int r = wj * 32 + n * 16 + (l & 15);
                    const int c = (kc * 4 + (l >> 4)) ^ (r & 7);
                    bq[kc][n] = *(const bf16x8*)(SmB + cur * 8192 + r * 64 + c * 8);
                }
            }
            asm volatile("s_waitcnt lgkmcnt(0)" ::: "memory");
            __builtin_amdgcn_s_barrier();
            __builtin_amdgcn_sched_barrier(0);
            #pragma unroll
            for (int kc = 0; kc < 2; ++kc)
                #pragma unroll
                for (int m = 0; m < 2; ++m)
                    #pragma unroll
                    for (int n = 0; n < 2; ++n)
                        acc[s][m][n] = __builtin_amdgcn_mfma_f32_16x16x32_bf16(
                            af[kc][m], bq[kc][n], acc[s][m][n], 0, 0, 0);
        }
    }

    #pragma unroll
    for (int n = 0; n < 2; ++n) {
        const int jg = jt + wj * 32 + n * 16 + (l & 15);
        float inv[4];
        #pragma unroll
        for (int s = 0; s < 4; ++s) inv[s] = inv_na[s * R_ + b * N_ + jg];
        #pragma unroll
        for (int m = 0; m < 2; ++m)
            #pragma unroll
            for (int q = 0; q < 4; ++q) {
                const int il = itl + wi * 32 + m * 16 + (l >> 4) * 4 + q;
                float e[4]; float sum = 0.f;
                #pragma unroll
                for (int s = 0; s < 4; ++s) { e[s] = __expf(acc[s][m][n][q] * inv[s]); sum += e[s]; }
                const float rs = 1.0f / sum;
                #pragma unroll
                for (int s = 0; s < 4; ++s)
                    whalf[((size_t)(s * B_ + b) << 19) + (size_t)il * 1024 + jg] = f2b(e[s] * rs);
            }
    }
}

// ---------------- weighted v2 + T1 remap: 128x128 tile (recon config) ----------------
__global__ __launch_bounds__(256, 2) void k_gemm_weighted(
    const u16* __restrict__ whalf, const u16* __restrict__ arawT,
    u16* __restrict__ weighted, const int half)
{
    __shared__ u16 SA[2 * 128 * 64];
    __shared__ u16 SB[2 * 128 * 64];
    // 256 blocks: wgid fields (sb:5 | mt:2 | nt:1); 8 siblings of one sb (sharing
    // whalf/arawT panels) stay within one 32-wgid XCD chunk.
    const int wgid = xcd_wgid256(blockIdx.x);
    const int nt   = (wgid & 1) * 128;
    const int mt   = ((wgid >> 1) & 3) * 128;
    const int sb   = wgid >> 3;
    const int s = sb >> 3, b = sb & 7;
    f32x4 acc[4][4];
    #pragma unroll
    for (int m = 0; m < 4; ++m)
        #pragma unroll
        for (int n = 0; n < 4; ++n) acc[m][n] = (f32x4){0.f, 0.f, 0.f, 0.f};
    gemm_dbuf<2, 2, 4, 4>(whalf + ((size_t)sb << 19) + (size_t)mt * 1024,
                          arawT + ((size_t)sb << 18) + (size_t)nt * 1024,
                          1024, 1024, 1024, SA, SB, acc);
    const int l = threadIdx.x & 63, wv = threadIdx.x >> 6;
    const int wm = wv >> 1, wn = wv & 1;
    #pragma unroll
    for (int m = 0; m < 4; ++m)
        #pragma unroll
        for (int n = 0; n < 4; ++n)
            #pragma unroll
            for (int q = 0; q < 4; ++q) {
                const int i = half * 512 + mt + wm * 64 + m * 16 + (l >> 4) * 4 + q;
                const int d = nt + wn * 64 + n * 16 + (l & 15);
                weighted[(size_t)(b * N_ + i) * 1024 + s * 256 + d] = f2b(acc[m][n][q]);
            }
}

// ---------------- recon + T1 remap: out = weighted . WrT^T + brsum, 128x128 tile ----------------
__global__ __launch_bounds__(256, 2) void k_gemm_recon(
    const u16* __restrict__ weighted, const u16* __restrict__ WrT,
    const float* __restrict__ brsum, float* __restrict__ out)
{
    __shared__ u16 SA[2 * 128 * 64];
    __shared__ u16 SB[2 * 128 * 64];
    const int wgid = xcd_wgid512(blockIdx.x);
    const int nt   = (wgid & 7) * 128;
    const int mt   = (wgid >> 3) * 128;
    f32x4 acc[4][4];
    #pragma unroll
    for (int m = 0; m < 4; ++m)
        #pragma unroll
        for (int n = 0; n < 4; ++n) acc[m][n] = (f32x4){0.f, 0.f, 0.f, 0.f};
    gemm_dbuf<2, 2, 4, 4>(weighted + (size_t)mt * 1024, WrT + (size_t)nt * 1024,
                          1024, 1024, 1024, SA, SB, acc);
    const int l = threadIdx.x & 63, wv = threadIdx.x >> 6;
    const int wm = wv >> 1, wn = wv & 1;
    #pragma unroll
    for (int m = 0; m < 4; ++m)
        #pragma unroll
        for (int n = 0; n < 4; ++n)
            #pragma unroll
            for (int q = 0; q < 4; ++q) {
                const int row = mt + wm * 64 + m * 16 + (l >> 4) * 4 + q;
                const int col = nt + wn * 64 + n * 16 + (l & 15);
                out[(size_t)row * 1024 + col] = acc[m][n][q] + brsum[col];
            }
}

extern "C" void kernel_launch(void* const* d_in, const int* in_sizes, int n_in,
                              void* d_out, int out_size, void* d_ws, size_t ws_size,
                              hipStream_t stream) {
    const float* hx = (const float*)d_in[0];
    const float* ha = (const float*)d_in[1];
    const float* Wp = (const float*)d_in[2];
    const float* bp = (const float*)d_in[3];
    const float* Wr = (const float*)d_in[4];
    const float* br = (const float*)d_in[5];
    float* out = (float*)d_out;

    // Workspace map (<=128 MiB):
    //  [0,16)  weighted
    //  [32,34) WpT  [34,36) WrT  [36,+4K) brsum  [36M+256K,+128K) inv_na
    //  [37,53) xnb   [53,69) araw   [69,85) arawT   [85,117) w_half (32 MiB)
    char* W = (char*)d_ws;
    u16* WpT      = (u16*)(W + (32ull << 20));
    u16* WrT      = (u16*)(W + (34ull << 20));
    float* brsum  = (float*)(W + (36ull << 20));
    float* inv_na = (float*)(W + (36ull << 20) + (256ull << 10));
    u16* xnb      = (u16*)(W + (37ull << 20));
    u16* araw     = (u16*)(W + (53ull << 20));
    u16* arawT    = (u16*)(W + (69ull << 20));
    u16* whalf    = (u16*)(W + (85ull << 20));
    u16* weighted = (u16*)(W);

    // 1) merged prep: WpT + WrT + brsum
    k_prep<<<dim3(516), dim3(256), 0, stream>>>(Wp, Wr, br, WpT, WrT, brsum);

    // 2) fused projection + norm (fp32-direct A, T1 remap)
    k_proj_norm<<<dim3(512), dim3(512), 0, stream>>>(hx, ha, WpT, bp, xnb, araw, inv_na);

    // 3) transpose araw -> arawT [(s,b)][d][j]
    k_tc_araw<<<dim3(16, 4, 32), dim3(256), 0, stream>>>(araw, arawT);

    // 4) sim+softmax -> w_half; weighted GEMM (128x128), ping-pong over i-halves
    for (int half = 0; half < 2; ++half) {
        k_sim_v3<<<dim3(512), dim3(512), 0, stream>>>(xnb, araw, inv_na, whalf, half);
        k_gemm_weighted<<<dim3(256), dim3(256), 0, stream>>>(whalf, arawT, weighted, half);
    }

    // 5) reconstruct + bias (T1 remap)
    k_gemm_recon<<<dim3(512), dim3(256), 0, stream>>>(weighted, WrT, brsum, out);
}

// Round 15
// 155.408 us; speedup vs baseline: 1.0501x; 1.0501x over previous
//
#include <hip/hip_runtime.h>
#include <hip/hip_bf16.h>

#define S_ 4
#define H_ 1024
#define D_ 256
#define B_ 8
#define N_ 1024
#define R_ (B_*N_)   /* 8192 */
#define EPS_ 1e-8f

typedef float f32x4 __attribute__((ext_vector_type(4)));
typedef short bf16x8 __attribute__((ext_vector_type(8)));
typedef unsigned short u16;

__device__ __forceinline__ u16 f2b(float f) {
    union { __bf16 h; u16 u; } cv; cv.h = (__bf16)f; return cv.u;
}

__device__ __forceinline__ void gload16(const void* g, void* l) {
    __builtin_amdgcn_global_load_lds((const __attribute__((address_space(1))) void*)g,
                                     (__attribute__((address_space(3))) void*)l, 16, 0, 0);
}

// T1 XCD-chunked remap (bijective for nwg=512): siblings with consecutive wgid
// share one 64-wgid chunk -> one XCD's L2 (assumes bid%8 round-robin dispatch).
__device__ __forceinline__ int xcd_wgid512(int bid) {
    return (bid & 7) * 64 + (bid >> 3);
}

// ---------------- prep (merged): Wp^T, Wr^T, brsum in one launch ----------------
__device__ __forceinline__ void tc64(const float* __restrict__ src, int lds_,
                                     u16* __restrict__ dst, int ldd) {
    __shared__ float t[64][65];
    const int tid = threadIdx.x;
    const int rr = tid >> 4;
    const int cc = (tid & 15) * 4;
    #pragma unroll
    for (int p = 0; p < 4; ++p) {
        const int r = rr + p * 16;
        const float4 v = *(const float4*)(src + (size_t)r * lds_ + cc);
        t[r][cc] = v.x; t[r][cc + 1] = v.y; t[r][cc + 2] = v.z; t[r][cc + 3] = v.w;
    }
    __syncthreads();
    #pragma unroll
    for (int p = 0; p < 4; ++p) {
        const int c = rr + p * 16;
        union { u16 u[4]; uint2 v; } o;
        o.u[0] = f2b(t[cc + 0][c]); o.u[1] = f2b(t[cc + 1][c]);
        o.u[2] = f2b(t[cc + 2][c]); o.u[3] = f2b(t[cc + 3][c]);
        *(uint2*)(dst + (size_t)c * ldd + cc) = o.v;
    }
}

__global__ __launch_bounds__(256) void k_prep(
    const float* __restrict__ Wp, const float* __restrict__ Wr, const float* __restrict__ br,
    u16* __restrict__ WpT, u16* __restrict__ WrT, float* __restrict__ brsum)
{
    const int bid = blockIdx.x;
    if (bid < 256) {                       // Wp transpose
        const int s = bid >> 6;
        const int r0 = (bid & 15) * 64;    // h
        const int c0 = ((bid >> 4) & 3) * 64;  // d
        tc64(Wp + (size_t)s * H_ * D_ + (size_t)r0 * D_ + c0, D_,
             WpT + (size_t)s * D_ * H_ + (size_t)c0 * H_ + r0, H_);
    } else if (bid < 512) {                // Wr transpose
        const int b2 = bid - 256;
        const int c0 = (b2 & 15) * 64;     // h
        const int r0 = (b2 >> 4) * 64;     // sd
        tc64(Wr + (size_t)r0 * H_ + c0, H_,
             WrT + (size_t)c0 * H_ + r0, H_);
    } else {                               // brsum
        const int h = (bid - 512) * 256 + threadIdx.x;
        if (h < H_) brsum[h] = br[h] + br[H_ + h] + br[2 * H_ + h] + br[3 * H_ + h];
    }
}

// ---------------- bf16 64x64 transpose: araw [r][s*256+d] -> arawT [(s,b)][d][j] ----------------
__global__ __launch_bounds__(256) void k_tc_araw(const u16* __restrict__ src, u16* __restrict__ dst) {
    const int sb = blockIdx.z, s = sb >> 3, b = sb & 7;
    const int j0 = blockIdx.x * 64, d0 = blockIdx.y * 64;
    __shared__ u16 tile[64][68];
    const int t = threadIdx.x;
    const int r = t >> 4, c4 = (t & 15) * 4;
    #pragma unroll
    for (int p = 0; p < 4; ++p) {
        const int row = p * 16 + r;
        *(uint2*)&tile[row][c4] =
            *(const uint2*)(src + (size_t)(b * N_ + j0 + row) * 1024 + s * 256 + d0 + c4);
    }
    __syncthreads();
    #pragma unroll
    for (int p = 0; p < 4; ++p) {
        const int orow = p * 16 + r;      // d-index
        union { u16 u[4]; uint2 v; } o;
        o.u[0] = tile[c4 + 0][orow]; o.u[1] = tile[c4 + 1][orow];
        o.u[2] = tile[c4 + 2][orow]; o.u[3] = tile[c4 + 3][orow];
        *(uint2*)(dst + ((size_t)sb << 18) + (size_t)(d0 + orow) * 1024 + j0 + c4) = o.v;
    }
}

// ============ reusable dbuf BK=64 GEMM core: C = A(TMxK) . B^T(TNxK) ============
template<int WROWS, int WCOLS, int MFR, int NFR>
__device__ __forceinline__ void gemm_dbuf(
    const u16* __restrict__ Ag, const u16* __restrict__ Bg,
    int lda, int ldb, int K, u16* SA, u16* SB, f32x4 (&acc)[MFR][NFR])
{
    constexpr int NT = WROWS * WCOLS * 64;
    constexpr int TM = WROWS * MFR * 16;
    constexpr int TN = WCOLS * NFR * 16;
    constexpr int CA = TM * 8 / NT;       // 16B chunks per thread for A
    constexpr int CB = TN * 8 / NT;
    constexpr int L  = CA + CB;           // vmem instrs per STAGE per thread
    const int tid = threadIdx.x, l = tid & 63, wv = tid >> 6;
    const int wm = wv / WCOLS, wn = wv % WCOLS;
    const int nsteps = K / 64;

    auto STAGE = [&](int buf, int k0) {
        #pragma unroll
        for (int i = 0; i < CA; ++i) {
            const int ci = i * NT + tid;
            const int row = ci >> 3, c = ci & 7, cs = c ^ (row & 7);
            gload16(Ag + (size_t)row * lda + k0 + cs * 8, SA + buf * TM * 64 + ci * 8);
        }
        #pragma unroll
        for (int i = 0; i < CB; ++i) {
            const int ci = i * NT + tid;
            const int row = ci >> 3, c = ci & 7, cs = c ^ (row & 7);
            gload16(Bg + (size_t)row * ldb + k0 + cs * 8, SB + buf * TN * 64 + ci * 8);
        }
    };

    STAGE(0, 0);
    for (int t = 0; t < nsteps; ++t) {
        const int cur = t & 1;
        if (t < nsteps - 1) {
            STAGE(cur ^ 1, (t + 1) * 64);
            if constexpr (L == 3)      asm volatile("s_waitcnt vmcnt(3)" ::: "memory");
            else if constexpr (L == 6) asm volatile("s_waitcnt vmcnt(6)" ::: "memory");
            else if constexpr (L == 8) asm volatile("s_waitcnt vmcnt(8)" ::: "memory");
            else                       asm volatile("s_waitcnt vmcnt(0)" ::: "memory");
        } else {
            asm volatile("s_waitcnt vmcnt(0)" ::: "memory");
        }
        __builtin_amdgcn_s_barrier();
        __builtin_amdgcn_sched_barrier(0);
        bf16x8 af[2][MFR], bq[2][NFR];
        #pragma unroll
        for (int kc = 0; kc < 2; ++kc) {
            #pragma unroll
            for (int m = 0; m < MFR; ++m) {
                const int r = wm * MFR * 16 + m * 16 + (l & 15);
                const int c = (kc * 4 + (l >> 4)) ^ (r & 7);
                af[kc][m] = *(const bf16x8*)(SA + cur * TM * 64 + r * 64 + c * 8);
            }
            #pragma unroll
            for (int n = 0; n < NFR; ++n) {
                const int r = wn * NFR * 16 + n * 16 + (l & 15);
                const int c = (kc * 4 + (l >> 4)) ^ (r & 7);
                bq[kc][n] = *(const bf16x8*)(SB + cur * TN * 64 + r * 64 + c * 8);
            }
        }
        asm volatile("s_waitcnt lgkmcnt(0)" ::: "memory");
        __builtin_amdgcn_s_barrier();
        __builtin_amdgcn_sched_barrier(0);
        #pragma unroll
        for (int kc = 0; kc < 2; ++kc)
            #pragma unroll
            for (int m = 0; m < MFR; ++m)
                #pragma unroll
                for (int n = 0; n < NFR; ++n)
                    acc[m][n] = __builtin_amdgcn_mfma_f32_16x16x32_bf16(af[kc][m], bq[kc][n], acc[m][n], 0, 0, 0);
    }
}

// ---------------- proj (fused norm) v7 + T1 remap: fp32-direct A, BK=32 dbuf ----------------
__global__ __launch_bounds__(512, 4) void k_proj_norm(
    const float* __restrict__ hx, const float* __restrict__ ha,
    const u16* __restrict__ WpT, const float* __restrict__ bp,
    u16* __restrict__ xnb, u16* __restrict__ araw, float* __restrict__ inv_na)
{
    __shared__ u16 SA[2][128][32];     // 16 KB
    __shared__ u16 SB[2][256][32];     // 32 KB
    __shared__ float normbuf[128][4];  //  2 KB

    const int wgid = xcd_wgid512(blockIdx.x);
    const int s    = wgid & 3;
    const int is_a = (wgid >> 2) & 1;
    const int rt   = (wgid >> 3) * 128;
    const int tid = threadIdx.x;
    const int l = tid & 63, wv = tid >> 6;
    const int wm = wv >> 2, wn = wv & 3;  // 2 x 4, wave tile 64x64
    const float* __restrict__ Ag = (is_a ? ha : hx) + (size_t)rt * 1024;
    const u16* __restrict__ Bg = WpT + (size_t)(s * 256) * 1024;

    const int arow = tid >> 2, aslot = tid & 3;
    const int acs  = (aslot - (arow >> 1)) & 3;
    const float* __restrict__ Ap = Ag + (size_t)arow * 1024 + acs * 8;

    f32x4 acc[4][4];
    #pragma unroll
    for (int m = 0; m < 4; ++m)
        #pragma unroll
        for (int n = 0; n < 4; ++n) acc[m][n] = (f32x4){0.f, 0.f, 0.f, 0.f};

    float4 a0[2], a1[2];   // two A reg sets (tile parity)
    auto ALOAD = [&](float4 (&r)[2], int k0) {
        r[0] = *(const float4*)(Ap + k0);
        r[1] = *(const float4*)(Ap + k0 + 4);
    };
    auto AWRITE = [&](const float4 (&r)[2], int buf) {
        union { u16 u[8]; uint4 v; } o;
        o.u[0] = f2b(r[0].x); o.u[1] = f2b(r[0].y); o.u[2] = f2b(r[0].z); o.u[3] = f2b(r[0].w);
        o.u[4] = f2b(r[1].x); o.u[5] = f2b(r[1].y); o.u[6] = f2b(r[1].z); o.u[7] = f2b(r[1].w);
        *(uint4*)&SA[buf][arow][aslot * 8] = o.v;
    };
    auto BSTAGE = [&](int buf, int k0) {
        #pragma unroll
        for (int i = 0; i < 2; ++i) {
            const int ci = i * 512 + tid;
            const int row = ci >> 2, c = ci & 3, cs = (c - (row >> 1)) & 3;
            gload16(Bg + (size_t)row * 1024 + k0 + cs * 8, &SB[buf][row][c * 8]);
        }
    };
    auto COMPUTE = [&](int cur) {
        bf16x8 af[4], bq[4];
        #pragma unroll
        for (int m = 0; m < 4; ++m) {
            const int r = wm * 64 + m * 16 + (l & 15);
            const int c = ((l >> 4) + (r >> 1)) & 3;
            af[m] = *(const bf16x8*)&SA[cur][r][c * 8];
        }
        #pragma unroll
        for (int n = 0; n < 4; ++n) {
            const int r = wn * 64 + n * 16 + (l & 15);
            const int c = ((l >> 4) + (r >> 1)) & 3;
            bq[n] = *(const bf16x8*)&SB[cur][r][c * 8];
        }
        asm volatile("s_waitcnt lgkmcnt(0)" ::: "memory");
        __builtin_amdgcn_sched_barrier(0);
        __builtin_amdgcn_s_barrier();        // free cur for next iter's staging
        __builtin_amdgcn_sched_barrier(0);
        #pragma unroll
        for (int m = 0; m < 4; ++m)
            #pragma unroll
            for (int n = 0; n < 4; ++n)
                acc[m][n] = __builtin_amdgcn_mfma_f32_16x16x32_bf16(af[m], bq[n], acc[m][n], 0, 0, 0);
    };
    auto BODY = [&](int t, float4 (&wset)[2], float4 (&lset)[2], int cur, bool doload) {
        asm volatile("s_waitcnt vmcnt(2)" ::: "memory");   // retire A(t+1) (oldest 2)
        __builtin_amdgcn_sched_barrier(0);
        AWRITE(wset, cur ^ 1);
        if (doload) ALOAD(lset, (t + 2) * 32);
        BSTAGE(cur ^ 1, (t + 1) * 32);
        if (doload) asm volatile("s_waitcnt vmcnt(4)" ::: "memory");  // retire B(t)
        else        asm volatile("s_waitcnt vmcnt(2)" ::: "memory");
        asm volatile("s_waitcnt lgkmcnt(0)" ::: "memory"); // A(t) writes visible
        __builtin_amdgcn_sched_barrier(0);
        __builtin_amdgcn_s_barrier();        // publish tile t
        __builtin_amdgcn_sched_barrier(0);
        COMPUTE(cur);
    };

    ALOAD(a0, 0);
    ALOAD(a1, 32);
    BSTAGE(0, 0);
    asm volatile("s_waitcnt vmcnt(4)" ::: "memory");       // retire A(0)
    __builtin_amdgcn_sched_barrier(0);
    AWRITE(a0, 0);

    for (int tt = 0; tt < 30; tt += 2) {
        BODY(tt,     a1, a0, 0, true);
        BODY(tt + 1, a0, a1, 1, true);
    }
    BODY(30, a1, a0, 0, false);
    asm volatile("s_waitcnt vmcnt(0)" ::: "memory");
    asm volatile("s_waitcnt lgkmcnt(0)" ::: "memory");
    __builtin_amdgcn_sched_barrier(0);
    __builtin_amdgcn_s_barrier();
    __builtin_amdgcn_sched_barrier(0);
    COMPUTE(1);

    // ---- epilogue: bias, row L2-norm over the 256-col subspace, write bf16 ----
    float bv[4];
    #pragma unroll
    for (int n = 0; n < 4; ++n) bv[n] = bp[s * 256 + wn * 64 + n * 16 + (l & 15)];
    #pragma unroll
    for (int m = 0; m < 4; ++m)
        #pragma unroll
        for (int n = 0; n < 4; ++n)
            #pragma unroll
            for (int q = 0; q < 4; ++q) acc[m][n][q] += bv[n];

    float ss[4][4];
    #pragma unroll
    for (int m = 0; m < 4; ++m)
        #pragma unroll
        for (int q = 0; q < 4; ++q) {
            float v = 0.f;
            #pragma unroll
            for (int n = 0; n < 4; ++n) v += acc[m][n][q] * acc[m][n][q];
            ss[m][q] = v;
        }
    #pragma unroll
    for (int off = 1; off <= 8; off <<= 1)
        #pragma unroll
        for (int m = 0; m < 4; ++m)
            #pragma unroll
            for (int q = 0; q < 4; ++q) ss[m][q] += __shfl_xor(ss[m][q], off, 64);
    if ((l & 15) == 0) {
        #pragma unroll
        for (int m = 0; m < 4; ++m)
            #pragma unroll
            for (int q = 0; q < 4; ++q)
                normbuf[wm * 64 + m * 16 + (l >> 4) * 4 + q][wn] = ss[m][q];
    }
    __syncthreads();
    float sc[4][4];
    #pragma unroll
    for (int m = 0; m < 4; ++m)
        #pragma unroll
        for (int q = 0; q < 4; ++q) {
            const int rl = wm * 64 + m * 16 + (l >> 4) * 4 + q;
            const float tot = normbuf[rl][0] + normbuf[rl][1] + normbuf[rl][2] + normbuf[rl][3];
            sc[m][q] = 1.0f / fmaxf(sqrtf(tot), EPS_);
        }
    if (!is_a) {
        #pragma unroll
        for (int m = 0; m < 4; ++m)
            #pragma unroll
            for (int n = 0; n < 4; ++n)
                #pragma unroll
                for (int q = 0; q < 4; ++q) {
                    const int rl = wm * 64 + m * 16 + (l >> 4) * 4 + q;
                    xnb[(size_t)(rt + rl) * 1024 + s * 256 + wn * 64 + n * 16 + (l & 15)] =
                        f2b(acc[m][n][q] * sc[m][q]);
                }
    } else {
        #pragma unroll
        for (int m = 0; m < 4; ++m)
            #pragma unroll
            for (int n = 0; n < 4; ++n)
                #pragma unroll
                for (int q = 0; q < 4; ++q) {
                    const int rl = wm * 64 + m * 16 + (l >> 4) * 4 + q;
                    araw[(size_t)(rt + rl) * 1024 + s * 256 + wn * 64 + n * 16 + (l & 15)] =
                        f2b(acc[m][n][q]);
                }
        if (wn == 0 && (l & 15) == 0) {
            #pragma unroll
            for (int m = 0; m < 4; ++m)
                #pragma unroll
                for (int q = 0; q < 4; ++q) {
                    const int rl = wm * 64 + m * 16 + (l >> 4) * 4 + q;
                    inv_na[s * R_ + rt + rl] = sc[m][q];
                }
        }
    }
}

// ---------------- sim v3 + T1 remap: TM=64, dbuf, fused softmax(s) ----------------
__global__ __launch_bounds__(512, 4) void k_sim_v3(
    const u16* __restrict__ xnb, const u16* __restrict__ araw,
    const float* __restrict__ inv_na, u16* __restrict__ whalf, const int half)
{
    __shared__ u16 SmA[2 * 64 * 64];
    __shared__ u16 SmB[2 * 128 * 64];
    const int wgid = xcd_wgid512(blockIdx.x);
    const int jt   = (wgid & 7) * 128;
    const int itl  = ((wgid >> 3) & 7) * 64;
    const int b    = wgid >> 6;
    const int it  = half * 512 + itl;
    const int tid = threadIdx.x, l = tid & 63, wv = tid >> 6;  // 8 waves
    const int wi = wv >> 2, wj = wv & 3;         // 2 x 4 -> wave tile 32 x 32 (per s)
    const u16* __restrict__ Ag = xnb  + (size_t)(b * N_ + it) * 1024;
    const u16* __restrict__ Bg = araw + (size_t)(b * N_ + jt) * 1024;

    f32x4 acc[4][2][2];  // [s][m][n]
    #pragma unroll
    for (int s = 0; s < 4; ++s)
        #pragma unroll
        for (int m = 0; m < 2; ++m)
            #pragma unroll
            for (int n = 0; n < 2; ++n) acc[s][m][n] = (f32x4){0.f, 0.f, 0.f, 0.f};

    auto STAGE = [&](int buf, int t) {
        const int k0 = t * 64;
        {
            const int ci = tid;
            const int row = ci >> 3, c = ci & 7, cs = c ^ (row & 7);
            gload16(Ag + (size_t)row * 1024 + k0 + cs * 8, SmA + buf * 4096 + ci * 8);
        }
        #pragma unroll
        for (int i = 0; i < 2; ++i) {
            const int ci = i * 512 + tid;
            const int row = ci >> 3, c = ci & 7, cs = c ^ (row & 7);
            gload16(Bg + (size_t)row * 1024 + k0 + cs * 8, SmB + buf * 8192 + ci * 8);
        }
    };

    STAGE(0, 0);
    #pragma unroll
    for (int s = 0; s < 4; ++s) {
        #pragma unroll
        for (int kk = 0; kk < 4; ++kk) {
            const int t = s * 4 + kk;
            const int cur = t & 1;
            if (t < 15) {
                STAGE(cur ^ 1, t + 1);
                asm volatile("s_waitcnt vmcnt(3)" ::: "memory");
            } else {
                asm volatile("s_waitcnt vmcnt(0)" ::: "memory");
            }
            __builtin_amdgcn_s_barrier();
            __builtin_amdgcn_sched_barrier(0);
            bf16x8 af[2][2], bq[2][2];
            #pragma unroll
            for (int kc = 0; kc < 2; ++kc) {
                #pragma unroll
                for (int m = 0; m < 2; ++m) {
                    const int r = wi * 32 + m * 16 + (l & 15);
                    const int c = (kc * 4 + (l >> 4)) ^ (r & 7);
                    af[kc][m] = *(const bf16x8*)(SmA + cur * 4096 + r * 64 + c * 8);
                }
                #pragma unroll
                for (int n = 0; n < 2; ++n) {
                    const int r = wj * 32 + n * 16 + (l & 15);
                    const int c = (kc * 4 + (l >> 4)) ^ (r & 7);
                    bq[kc][n] = *(const bf16x8*)(SmB + cur * 8192 + r * 64 + c * 8);
                }
            }
            asm volatile("s_waitcnt lgkmcnt(0)" ::: "memory");
            __builtin_amdgcn_s_barrier();
            __builtin_amdgcn_sched_barrier(0);
            #pragma unroll
            for (int kc = 0; kc < 2; ++kc)
                #pragma unroll
                for (int m = 0; m < 2; ++m)
                    #pragma unroll
                    for (int n = 0; n < 2; ++n)
                        acc[s][m][n] = __builtin_amdgcn_mfma_f32_16x16x32_bf16(
                            af[kc][m], bq[kc][n], acc[s][m][n], 0, 0, 0);
        }
    }

    #pragma unroll
    for (int n = 0; n < 2; ++n) {
        const int jg = jt + wj * 32 + n * 16 + (l & 15);
        float inv[4];
        #pragma unroll
        for (int s = 0; s < 4; ++s) inv[s] = inv_na[s * R_ + b * N_ + jg];
        #pragma unroll
        for (int m = 0; m < 2; ++m)
            #pragma unroll
            for (int q = 0; q < 4; ++q) {
                const int il = itl + wi * 32 + m * 16 + (l >> 4) * 4 + q;
                float e[4]; float sum = 0.f;
                #pragma unroll
                for (int s = 0; s < 4; ++s) { e[s] = __expf(acc[s][m][n][q] * inv[s]); sum += e[s]; }
                const float rs = 1.0f / sum;
                #pragma unroll
                for (int s = 0; s < 4; ++s)
                    whalf[((size_t)(s * B_ + b) << 19) + (size_t)il * 1024 + jg] = f2b(e[s] * rs);
            }
    }
}

// ---------------- weighted + T1 remap: w_half . arawT^T (per s,b), 64x128 tile ----------------
__global__ __launch_bounds__(256, 2) void k_gemm_weighted(
    const u16* __restrict__ whalf, const u16* __restrict__ arawT,
    u16* __restrict__ weighted, const int half)
{
    __shared__ u16 SA[2 * 64 * 64];
    __shared__ u16 SB[2 * 128 * 64];
    // T1: wgid fields (sb:5 | mt:3 | nt:1); 16 siblings of one sb share whalf/arawT panels.
    const int wgid = xcd_wgid512(blockIdx.x);
    const int nt   = (wgid & 1) * 128;
    const int mt   = ((wgid >> 1) & 7) * 64;
    const int sb   = wgid >> 4;
    const int s = sb >> 3, b = sb & 7;
    f32x4 acc[2][4];
    #pragma unroll
    for (int m = 0; m < 2; ++m)
        #pragma unroll
        for (int n = 0; n < 4; ++n) acc[m][n] = (f32x4){0.f, 0.f, 0.f, 0.f};
    gemm_dbuf<2, 2, 2, 4>(whalf + ((size_t)sb << 19) + (size_t)mt * 1024,
                          arawT + ((size_t)sb << 18) + (size_t)nt * 1024,
                          1024, 1024, 1024, SA, SB, acc);
    const int l = threadIdx.x & 63, wv = threadIdx.x >> 6;
    const int wm = wv >> 1, wn = wv & 1;
    #pragma unroll
    for (int m = 0; m < 2; ++m)
        #pragma unroll
        for (int n = 0; n < 4; ++n)
            #pragma unroll
            for (int q = 0; q < 4; ++q) {
                const int i = half * 512 + mt + wm * 32 + m * 16 + (l >> 4) * 4 + q;
                const int d = nt + wn * 64 + n * 16 + (l & 15);
                weighted[(size_t)(b * N_ + i) * 1024 + s * 256 + d] = f2b(acc[m][n][q]);
            }
}

// ---------------- recon + T1 remap: out = weighted . WrT^T + brsum, 128x128 tile ----------------
__global__ __launch_bounds__(256, 2) void k_gemm_recon(
    const u16* __restrict__ weighted, const u16* __restrict__ WrT,
    const float* __restrict__ brsum, float* __restrict__ out)
{
    __shared__ u16 SA[2 * 128 * 64];
    __shared__ u16 SB[2 * 128 * 64];
    // T1: wgid fields (mt:6 | nt:3); 8 nt-siblings (same mt -> same A panel) on one XCD.
    const int wgid = xcd_wgid512(blockIdx.x);
    const int nt   = (wgid & 7) * 128;
    const int mt   = (wgid >> 3) * 128;
    f32x4 acc[4][4];
    #pragma unroll
    for (int m = 0; m < 4; ++m)
        #pragma unroll
        for (int n = 0; n < 4; ++n) acc[m][n] = (f32x4){0.f, 0.f, 0.f, 0.f};
    gemm_dbuf<2, 2, 4, 4>(weighted + (size_t)mt * 1024, WrT + (size_t)nt * 1024,
                          1024, 1024, 1024, SA, SB, acc);
    const int l = threadIdx.x & 63, wv = threadIdx.x >> 6;
    const int wm = wv >> 1, wn = wv & 1;
    #pragma unroll
    for (int m = 0; m < 4; ++m)
        #pragma unroll
        for (int n = 0; n < 4; ++n)
            #pragma unroll
            for (int q = 0; q < 4; ++q) {
                const int row = mt + wm * 64 + m * 16 + (l >> 4) * 4 + q;
                const int col = nt + wn * 64 + n * 16 + (l & 15);
                out[(size_t)row * 1024 + col] = acc[m][n][q] + brsum[col];
            }
}

extern "C" void kernel_launch(void* const* d_in, const int* in_sizes, int n_in,
                              void* d_out, int out_size, void* d_ws, size_t ws_size,
                              hipStream_t stream) {
    const float* hx = (const float*)d_in[0];
    const float* ha = (const float*)d_in[1];
    const float* Wp = (const float*)d_in[2];
    const float* bp = (const float*)d_in[3];
    const float* Wr = (const float*)d_in[4];
    const float* br = (const float*)d_in[5];
    float* out = (float*)d_out;

    // Workspace map (<=128 MiB):
    //  [0,16)  weighted
    //  [32,34) WpT  [34,36) WrT  [36,+4K) brsum  [36M+256K,+128K) inv_na
    //  [37,53) xnb   [53,69) araw   [69,85) arawT   [85,117) w_half (32 MiB)
    char* W = (char*)d_ws;
    u16* WpT      = (u16*)(W + (32ull << 20));
    u16* WrT      = (u16*)(W + (34ull << 20));
    float* brsum  = (float*)(W + (36ull << 20));
    float* inv_na = (float*)(W + (36ull << 20) + (256ull << 10));
    u16* xnb      = (u16*)(W + (37ull << 20));
    u16* araw     = (u16*)(W + (53ull << 20));
    u16* arawT    = (u16*)(W + (69ull << 20));
    u16* whalf    = (u16*)(W + (85ull << 20));
    u16* weighted = (u16*)(W);

    // 1) merged prep: WpT + WrT + brsum
    k_prep<<<dim3(516), dim3(256), 0, stream>>>(Wp, Wr, br, WpT, WrT, brsum);

    // 2) fused projection + norm (fp32-direct A, T1 remap)
    k_proj_norm<<<dim3(512), dim3(512), 0, stream>>>(hx, ha, WpT, bp, xnb, araw, inv_na);

    // 3) transpose araw -> arawT [(s,b)][d][j]
    k_tc_araw<<<dim3(16, 4, 32), dim3(256), 0, stream>>>(araw, arawT);

    // 4) sim+softmax -> w_half; weighted GEMM, ping-pong over i-halves (T1 remap)
    for (int half = 0; half < 2; ++half) {
        k_sim_v3<<<dim3(512), dim3(512), 0, stream>>>(xnb, araw, inv_na, whalf, half);
        k_gemm_weighted<<<dim3(512), dim3(256), 0, stream>>>(whalf, arawT, weighted, half);
    }

    // 5) reconstruct + bias (T1 remap)
    k_gemm_recon<<<dim3(512), dim3(256), 0, stream>>>(weighted, WrT, brsum, out);
}